// Round 8
// baseline (622.738 us; speedup 1.0000x reference)
//
#include <hip/hip_runtime.h>
#include <hip/hip_bf16.h>

#define DEV __device__ __forceinline__

typedef float  f32x4  __attribute__((ext_vector_type(4)));
typedef __bf16 bf16x8 __attribute__((ext_vector_type(8)));

// ---------- helpers ----------
DEV unsigned short f2b(float x){
  union { float f; unsigned u; } v; v.f = x;
  unsigned r = v.u + 0x7FFFu + ((v.u >> 16) & 1u);
  return (unsigned short)(r >> 16);
}
DEV float b2f(unsigned short h){
  union { unsigned u; float f; } v; v.u = ((unsigned)h) << 16;
  return v.f;
}

// hollow-mask keep rule (verified vs python loops):
// zero iff (c'<=4 && c'+1<=r'<=6) || (r'<=4 && r'+1<=c'<=6), r'=min(r,14-r), c'=min(c,14-c)
struct CMap { short m[225]; };
constexpr CMap make_cmap(){
  CMap c{};
  int n = 0;
  for (int t = 0; t < 225; ++t){
    int r = t / 15, cc = t % 15;
    int rp = r < 14 - r ? r : 14 - r;
    int cp = cc < 14 - cc ? cc : 14 - cc;
    bool z = (cp <= 4 && rp >= cp + 1 && rp <= 6) || (rp <= 4 && cp >= rp + 1 && cp <= 6);
    c.m[t] = z ? (short)-1 : (short)(n++);
  }
  return c;
}
__constant__ CMap CMAP = make_cmap();

// LPT permutation: p sorted by nq(p) descending -> heavy blocks dispatch first,
// light blocks last (shrinks the end-of-kernel drain tail).
struct Perm { unsigned char v[64]; };
constexpr Perm make_lpt(){
  CMap cm = make_cmap();
  int nq[64] = {};
  for (int p = 0; p < 64; ++p){
    int py = p >> 3, px = p & 7, n = 0;
    for (int q = 0; q < 64; ++q){
      int qy = q >> 3, qx = q & 7;
      if (cm.m[(7 + qy - py) * 15 + (7 + qx - px)] >= 0) n++;
    }
    nq[p] = n;
  }
  Perm pr{};
  bool used[64] = {};
  for (int i = 0; i < 64; ++i){
    int best = 0, bv = -1;
    for (int p = 0; p < 64; ++p) if (!used[p] && nq[p] > bv){ bv = nq[p]; best = p; }
    used[best] = true;
    pr.v[i] = (unsigned char)best;
  }
  return pr;
}
__constant__ Perm LPT = make_lpt();

#define GLDS(gp, lp) __builtin_amdgcn_global_load_lds( \
    (const __attribute__((address_space(1))) void*)(const void*)(gp), \
    (__attribute__((address_space(3))) void*)(void*)(lp), 16, 0, 0)

// ---------- weight repack: w[O=256][I=256][15*15] f32 -> Wp[tap65][O][I] bf16 ----------
__global__ __launch_bounds__(256) void pack_w_k(
    const float* __restrict__ w0, const float* __restrict__ w1,
    const float* __restrict__ w2, unsigned short* __restrict__ Wp){
  __shared__ unsigned short sw[65][258];   // row stride 129 banks == 1 mod 32
  const int widx = blockIdx.x >> 8;
  const int o    = blockIdx.x & 255;
  const float4* src = (const float4*)((widx == 0 ? w0 : (widx == 1 ? w1 : w2)) + (size_t)o * 57600);
  unsigned short* dst = Wp + (size_t)widx * 65 * 65536 + (size_t)o * 256;
  for (int idx4 = threadIdx.x; idx4 < 14400; idx4 += 256){
    float4 val = src[idx4];
    int e = idx4 * 4;
    float vv[4] = {val.x, val.y, val.z, val.w};
#pragma unroll
    for (int j = 0; j < 4; ++j){
      int ee = e + j;
      int i = ee / 225;
      int t = ee - i * 225;
      short c = CMAP.m[t];
      if (c >= 0) sw[c][i] = f2b(vv[j]);
    }
  }
  __syncthreads();
  for (int idx = threadIdx.x; idx < 65 * 128; idx += 256){
    int t = idx >> 7, i2 = idx & 127;
    *(ushort2*)(dst + (size_t)t * 65536 + i2 * 2) = *(const ushort2*)&sw[t][i2 * 2];
  }
}

__global__ void pack_wo_k(const float4* __restrict__ wo, ushort4* __restrict__ WO){
  int i = blockIdx.x * 256 + threadIdx.x;   // 16384 total
  float4 a = wo[i];
  WO[i] = make_ushort4(f2b(a.x), f2b(a.y), f2b(a.z), f2b(a.w));
}

// ---------- input f32 -> bf16 ----------
__global__ void prep_k(const float4* __restrict__ q, const float4* __restrict__ k,
                       const float4* __restrict__ v, ushort4* __restrict__ xq,
                       ushort4* __restrict__ xk, ushort4* __restrict__ xv){
  int i = blockIdx.x * 256 + threadIdx.x;   // 524288 total
  float4 a = q[i]; xq[i] = make_ushort4(f2b(a.x), f2b(a.y), f2b(a.z), f2b(a.w));
  a = k[i];        xk[i] = make_ushort4(f2b(a.x), f2b(a.y), f2b(a.z), f2b(a.w));
  a = v[i];        xv[i] = make_ushort4(f2b(a.x), f2b(a.y), f2b(a.z), f2b(a.w));
}

// ---------- conv as block-gathered GEMM; split-K wave pairs ----------
// 768 work items = (64 p, 2 o-half, 6 = branch*2 + batch-half), 256 threads.
// XCD-chunked bijective remap (768%8==0) + LPT p-ordering within each group.
// 4 waves = (wn n-half) x (kp k-parity). Each wave computes the FULL-M 64x64
// tile of its n-half, on K-steps of its parity only -> B ds_reads halve
// (48 -> 32 b128 per block-step; the LDS read pipe was the measured
// dominant per-CU resource at ~82us vs MFMA ~45us).
// Epilogue: kp=1 writes f32 partials to LDS scratch (overlaying the tile
// buffers), kp=0 adds + bias (+ReLU) + stores.
template<bool RELU>
__global__ __launch_bounds__(256, 3) void conv_mm(
    const unsigned short* __restrict__ X0, const unsigned short* __restrict__ X1,
    const unsigned short* __restrict__ X2,
    const unsigned short* __restrict__ W0, const unsigned short* __restrict__ W1,
    const unsigned short* __restrict__ W2,
    const float* __restrict__ bias0, const float* __restrict__ bias1,
    const float* __restrict__ bias2,
    unsigned short* __restrict__ Yo0, unsigned short* __restrict__ Yo1,
    unsigned short* __restrict__ Yo2)
{
  // manual carve: A dbuf [2][64*64] @0 (8192), B dbuf [2][128*64] @8192 (16384)
  // epilogue overlays the same region as f32 scratch [2][64*64] (32KB).
  __shared__ unsigned short lds[24576];
  __shared__ int qtap[64];
  __shared__ int nq_sh;

  const int L   = blockIdx.x + 64 * blockIdx.y + 128 * blockIdx.z;
  const int swz = (L & 7) * 96 + (L >> 3);     // XCD-chunked bijective remap
  const int p     = LPT.v[swz & 63];           // LPT: heavy nq first in dispatch order
  const int o0    = ((swz >> 6) & 1) * 128;
  const int zz    = swz >> 7;
  const int br    = zz >> 1;
  const int brow0 = (zz & 1) * 64;
  const unsigned short* X    = br == 0 ? X0 : (br == 1 ? X1 : X2);
  const unsigned short* W    = br == 0 ? W0 : (br == 1 ? W1 : W2);
  const float*          bias = br == 0 ? bias0 : (br == 1 ? bias1 : bias2);
  unsigned short*       Y    = br == 0 ? Yo0 : (br == 1 ? Yo1 : Yo2);

  const int tid = threadIdx.x;
  if (tid == 0){
    int py = p >> 3, px = p & 7, m = 0;
    for (int q = 0; q < 64; ++q){
      int qy = q >> 3, qx = q & 7;
      int t = (7 + qy - py) * 15 + (7 + qx - px);
      short c = CMAP.m[t];
      if (c >= 0) qtap[m++] = (q << 8) | (int)c;
    }
    nq_sh = m;
  }
  __syncthreads();
  const int nq     = nq_sh;
  const int nsteps = nq * 4;   // even always

  const int wv_ = tid >> 6, ln = tid & 63;
  const int lr = ln & 15, lk = ln >> 4;
  const int wn = wv_ & 1;      // n-half: cols wn*64..wn*64+63
  const int kp = wv_ >> 1;     // k-parity: this wave computes steps with s&1==kp
  f32x4 acc[4][4] = {};        // [mm 16-row blocks of M=64][nn 16-col blocks of 64]

  auto stage = [&](int buf, int s){
    int e   = qtap[s >> 2];
    int kkc = (s & 3) * 64;
    int q   = e >> 8, tap = e & 255;
    int r = ln >> 3, c = ln & 7;
    unsigned short* lA = lds + buf * 4096;
    unsigned short* lB = lds + 8192 + buf * 8192;
#pragma unroll
    for (int r2 = 0; r2 < 2; ++r2){
      int rowb = r2 * 32 + wv_ * 8;
      int row  = rowb + r;
      int csw  = c ^ (row & 7);
      GLDS(X + (size_t)(brow0 + row) * 16384 + q * 256 + kkc + csw * 8, lA + rowb * 64);
    }
#pragma unroll
    for (int r2 = 0; r2 < 4; ++r2){
      int rowb = r2 * 32 + wv_ * 8;
      int row  = rowb + r;
      int csw  = c ^ (row & 7);
      GLDS(W + (size_t)tap * 65536 + (size_t)(o0 + row) * 256 + kkc + csw * 8, lB + rowb * 64);
    }
  };

  stage(0, 0);
  for (int s = 0; s < nsteps; ++s){
    int buf = s & 1;
    if (s + 1 < nsteps){
      stage(buf ^ 1, s + 1);
      asm volatile("s_waitcnt vmcnt(6)" ::: "memory");
    } else {
      asm volatile("s_waitcnt vmcnt(0)" ::: "memory");
    }
    __builtin_amdgcn_sched_barrier(0);
    __builtin_amdgcn_s_barrier();
    if ((s & 1) == kp){
      const unsigned short* lAb = lds + buf * 4096;
      const unsigned short* lBb = lds + 8192 + buf * 8192;
#pragma unroll
      for (int ks = 0; ks < 2; ++ks){
        bf16x8 a[4], bb[4];
        int cb = ks * 4 + lk;
#pragma unroll
        for (int mm = 0; mm < 4; ++mm){
          int row = mm * 16 + lr;
          a[mm] = *(const bf16x8*)&lAb[row * 64 + ((cb ^ (row & 7)) << 3)];
        }
#pragma unroll
        for (int nn = 0; nn < 4; ++nn){
          int row = wn * 64 + nn * 16 + lr;
          bb[nn] = *(const bf16x8*)&lBb[row * 64 + ((cb ^ (row & 7)) << 3)];
        }
#pragma unroll
        for (int mm = 0; mm < 4; ++mm)
#pragma unroll
          for (int nn = 0; nn < 4; ++nn)
            acc[mm][nn] = __builtin_amdgcn_mfma_f32_16x16x32_bf16(a[mm], bb[nn], acc[mm][nn], 0, 0, 0);
      }
    }
    __builtin_amdgcn_s_barrier();
  }

  // ---- split-K reduction: kp=1 partials -> LDS scratch; kp=0 adds & stores ----
  __syncthreads();                 // full semantics before overlaying lds
  float* scr = (float*)lds;        // [wn][64 rows][64 cols] f32, 32KB
  if (kp == 1){
#pragma unroll
    for (int mm = 0; mm < 4; ++mm)
#pragma unroll
      for (int nn = 0; nn < 4; ++nn)
#pragma unroll
        for (int rr = 0; rr < 4; ++rr){
          int row = mm * 16 + lk * 4 + rr;       // D: row=(lane>>4)*4+reg
          int col = nn * 16 + lr;                //    col=lane&15
          scr[wn * 4096 + row * 64 + col] = acc[mm][nn][rr];
        }
  }
  __syncthreads();
  if (kp == 0){
#pragma unroll
    for (int mm = 0; mm < 4; ++mm)
#pragma unroll
      for (int nn = 0; nn < 4; ++nn)
#pragma unroll
        for (int rr = 0; rr < 4; ++rr){
          int row = mm * 16 + lk * 4 + rr;
          int col = nn * 16 + lr;
          int b = brow0 + row, o = o0 + wn * 64 + col;
          float val = acc[mm][nn][rr] + scr[wn * 4096 + row * 64 + col] + bias[o];
          if (RELU) val = fmaxf(val, 0.f);
          Y[(size_t)(b * 64 + p) * 256 + o] = f2b(val);
        }
  }
}

// ---------- attention per (b,h): 64x64 scores, softmax, PV ----------
__global__ __launch_bounds__(256) void attn_k(
    const unsigned short* __restrict__ Yq, const unsigned short* __restrict__ Yk,
    const unsigned short* __restrict__ Yv, unsigned short* __restrict__ CC)
{
  __shared__ float qs[64][33], ksh[64][33], vs[64][33];
  __shared__ float sc[64][65];
  const int b = blockIdx.x >> 3, h = blockIdx.x & 7;
  const size_t base = (size_t)b * 16384 + h * 32;
  for (int idx = threadIdx.x; idx < 2048; idx += 256){
    int pq = idx >> 5, dk = idx & 31;
    size_t g = base + (size_t)pq * 256 + dk;
    qs[pq][dk]  = b2f(Yq[g]);
    ksh[pq][dk] = b2f(Yk[g]);
    vs[pq][dk]  = b2f(Yv[g]);
  }
  __syncthreads();
  {
    int r = threadIdx.x >> 2, qd = threadIdx.x & 3;
    float qv[32];
#pragma unroll
    for (int d = 0; d < 32; ++d) qv[d] = qs[r][d];
    for (int j = 0; j < 16; ++j){
      int pk = qd * 16 + j;
      float a = 0.f;
#pragma unroll
      for (int d = 0; d < 32; ++d) a += qv[d] * ksh[pk][d];
      sc[r][pk] = a * 0.17677669529663687f;  // 1/sqrt(32)
    }
  }
  __syncthreads();
  if (threadIdx.x < 64){
    int r = threadIdx.x;
    float m = -1e30f;
    for (int j = 0; j < 64; ++j) m = fmaxf(m, sc[r][j]);
    float ssum = 0.f;
    for (int j = 0; j < 64; ++j){ float e = __expf(sc[r][j] - m); sc[r][j] = e; ssum += e; }
    float inv = 1.f / ssum;
    for (int j = 0; j < 64; ++j) sc[r][j] *= inv;
  }
  __syncthreads();
  for (int idx = threadIdx.x; idx < 2048; idx += 256){
    int pq = idx >> 5, dk = idx & 31;
    float a = 0.f;
#pragma unroll
    for (int pk = 0; pk < 64; ++pk) a += sc[pq][pk] * vs[pk][dk];
    CC[base + (size_t)pq * 256 + dk] = f2b(a);
  }
}

// ---------- final linear: out[m][o] = sum_c CC[m][c]*wo[o][c] + bo[o] ----------
__global__ __launch_bounds__(256, 3) void fin_mm(
    const unsigned short* __restrict__ A, const unsigned short* __restrict__ Bw,
    const float* __restrict__ bo, float* __restrict__ out)
{
  __shared__ unsigned short lA[2][64 * 64];
  __shared__ unsigned short lB[2][128 * 64];
  const int m0 = blockIdx.x * 64;
  const int o0 = blockIdx.y * 128;
  const int tid = threadIdx.x;
  const int wv_ = tid >> 6, ln = tid & 63;
  const int lr = ln & 15, lk = ln >> 4;
  const int wm = wv_ >> 1, wn = wv_ & 1;
  f32x4 acc[2][4] = {};

  auto stage = [&](int buf, int s){
    int kkc = s * 64;
    int r = ln >> 3, c = ln & 7;
#pragma unroll
    for (int r2 = 0; r2 < 2; ++r2){
      int rowb = r2 * 32 + wv_ * 8;
      int row  = rowb + r;
      int csw  = c ^ (row & 7);
      GLDS(A + (size_t)(m0 + row) * 256 + kkc + csw * 8, &lA[buf][rowb * 64]);
    }
#pragma unroll
    for (int r2 = 0; r2 < 4; ++r2){
      int rowb = r2 * 32 + wv_ * 8;
      int row  = rowb + r;
      int csw  = c ^ (row & 7);
      GLDS(Bw + (size_t)(o0 + row) * 256 + kkc + csw * 8, &lB[buf][rowb * 64]);
    }
  };

  stage(0, 0);
  for (int s = 0; s < 4; ++s){
    int buf = s & 1;
    if (s < 3){
      stage(buf ^ 1, s + 1);
      asm volatile("s_waitcnt vmcnt(6)" ::: "memory");
    } else {
      asm volatile("s_waitcnt vmcnt(0)" ::: "memory");
    }
    __builtin_amdgcn_sched_barrier(0);
    __builtin_amdgcn_s_barrier();
#pragma unroll
    for (int ks = 0; ks < 2; ++ks){
      bf16x8 a[2], bb[4];
      int cb = ks * 4 + lk;
#pragma unroll
      for (int mm = 0; mm < 2; ++mm){
        int row = wm * 32 + mm * 16 + lr;
        a[mm] = *(const bf16x8*)&lA[buf][row * 64 + ((cb ^ (row & 7)) << 3)];
      }
#pragma unroll
      for (int nn = 0; nn < 4; ++nn){
        int row = wn * 64 + nn * 16 + lr;
        bb[nn] = *(const bf16x8*)&lB[buf][row * 64 + ((cb ^ (row & 7)) << 3)];
      }
#pragma unroll
      for (int mm = 0; mm < 2; ++mm)
#pragma unroll
        for (int nn = 0; nn < 4; ++nn)
          acc[mm][nn] = __builtin_amdgcn_mfma_f32_16x16x32_bf16(a[mm], bb[nn], acc[mm][nn], 0, 0, 0);
    }
    __builtin_amdgcn_s_barrier();
  }

#pragma unroll
  for (int mm = 0; mm < 2; ++mm)
#pragma unroll
    for (int nn = 0; nn < 4; ++nn)
#pragma unroll
      for (int rr = 0; rr < 4; ++rr){
        int row = wm * 32 + mm * 16 + lk * 4 + rr;
        int col = wn * 64 + nn * 16 + lr;
        out[(size_t)(m0 + row) * 256 + o0 + col] = acc[mm][nn][rr] + bo[o0 + col];
      }
}

// ---------- launch ----------
extern "C" void kernel_launch(void* const* d_in, const int* in_sizes, int n_in,
                              void* d_out, int out_size, void* d_ws, size_t ws_size,
                              hipStream_t stream){
  const float* q  = (const float*)d_in[0];
  const float* k  = (const float*)d_in[1];
  const float* v  = (const float*)d_in[2];
  const float* wk = (const float*)d_in[3];
  const float* bk = (const float*)d_in[4];
  const float* wq = (const float*)d_in[5];
  const float* bq = (const float*)d_in[6];
  const float* wv = (const float*)d_in[7];
  const float* bv = (const float*)d_in[8];
  const float* wo = (const float*)d_in[9];
  const float* bo = (const float*)d_in[10];
  float* out = (float*)d_out;

  constexpr size_t WPS = 65ull * 65536;   // packed weight elems (ushort)
  constexpr size_t XSZ = 2097152ull;      // [128][64][256] elems

  char* ws = (char*)d_ws;
  size_t off = 0;
  auto alloc = [&](size_t bytes){ void* p = ws + off; off += (bytes + 255) & ~(size_t)255; return p; };
  unsigned short* Wp  = (unsigned short*)alloc(3 * WPS * 2);
  unsigned short* WO  = (unsigned short*)alloc(65536 * 2);
  unsigned short* Xq  = (unsigned short*)alloc(XSZ * 2);
  unsigned short* Xk  = (unsigned short*)alloc(XSZ * 2);
  unsigned short* Xv  = (unsigned short*)alloc(XSZ * 2);
  unsigned short* Y1q = (unsigned short*)alloc(XSZ * 2);
  unsigned short* Y1k = (unsigned short*)alloc(XSZ * 2);
  unsigned short* Y1v = (unsigned short*)alloc(XSZ * 2);
  unsigned short* Y2q = (unsigned short*)alloc(XSZ * 2);
  unsigned short* Y2k = (unsigned short*)alloc(XSZ * 2);
  unsigned short* Y2v = (unsigned short*)alloc(XSZ * 2);
  unsigned short* CC  = (unsigned short*)alloc(XSZ * 2);
  (void)ws_size; (void)in_sizes; (void)n_in; (void)out_size;

  // pack order: widx 0=wq, 1=wk, 2=wv
  pack_w_k<<<dim3(768), 256, 0, stream>>>(wq, wk, wv, Wp);
  pack_wo_k<<<dim3(64), 256, 0, stream>>>((const float4*)wo, (ushort4*)WO);
  prep_k<<<dim3(2048), 256, 0, stream>>>((const float4*)q, (const float4*)k, (const float4*)v,
                                         (ushort4*)Xq, (ushort4*)Xk, (ushort4*)Xv);
  // conv1: q->wq,bq ; k->wk,bk ; v->wv,bv  (+ReLU)
  conv_mm<true><<<dim3(64, 2, 6), 256, 0, stream>>>(
      Xq, Xk, Xv, Wp, Wp + WPS, Wp + 2 * WPS, bq, bk, bv, Y1q, Y1k, Y1v);
  // conv2: q->wk,bk (!) ; k->wk,bk ; v->wv,bv  (no ReLU) — faithful to reference
  conv_mm<false><<<dim3(64, 2, 6), 256, 0, stream>>>(
      Y1q, Y1k, Y1v, Wp + WPS, Wp + WPS, Wp + 2 * WPS, bk, bk, bv, Y2q, Y2k, Y2v);
  attn_k<<<dim3(1024), 256, 0, stream>>>(Y2q, Y2k, Y2v, CC);
  fin_mm<<<dim3(128, 2), 256, 0, stream>>>(CC, WO, bo, out);
}

// Round 9
// 593.148 us; speedup vs baseline: 1.0499x; 1.0499x over previous
//
#include <hip/hip_runtime.h>
#include <hip/hip_bf16.h>

#define DEV __device__ __forceinline__

typedef float  f32x4  __attribute__((ext_vector_type(4)));
typedef __bf16 bf16x8 __attribute__((ext_vector_type(8)));

// ---------- helpers ----------
DEV unsigned short f2b(float x){
  union { float f; unsigned u; } v; v.f = x;
  unsigned r = v.u + 0x7FFFu + ((v.u >> 16) & 1u);
  return (unsigned short)(r >> 16);
}
DEV float b2f(unsigned short h){
  union { unsigned u; float f; } v; v.u = ((unsigned)h) << 16;
  return v.f;
}

// hollow-mask keep rule (verified vs python loops):
// zero iff (c'<=4 && c'+1<=r'<=6) || (r'<=4 && r'+1<=c'<=6), r'=min(r,14-r), c'=min(c,14-c)
struct CMap { short m[225]; };
constexpr CMap make_cmap(){
  CMap c{};
  int n = 0;
  for (int t = 0; t < 225; ++t){
    int r = t / 15, cc = t % 15;
    int rp = r < 14 - r ? r : 14 - r;
    int cp = cc < 14 - cc ? cc : 14 - cc;
    bool z = (cp <= 4 && rp >= cp + 1 && rp <= 6) || (rp <= 4 && cp >= rp + 1 && cp <= 6);
    c.m[t] = z ? (short)-1 : (short)(n++);
  }
  return c;
}
__constant__ CMap CMAP = make_cmap();

#define GLDS(gp, lp) __builtin_amdgcn_global_load_lds( \
    (const __attribute__((address_space(1))) void*)(const void*)(gp), \
    (__attribute__((address_space(3))) void*)(void*)(lp), 16, 0, 0)

// ---------- weight repack: w[O=256][I=256][15*15] f32 -> Wp[tap65][O][I] bf16 ----------
__global__ __launch_bounds__(256) void pack_w_k(
    const float* __restrict__ w0, const float* __restrict__ w1,
    const float* __restrict__ w2, unsigned short* __restrict__ Wp){
  __shared__ unsigned short sw[65][258];   // row stride 129 banks == 1 mod 32
  const int widx = blockIdx.x >> 8;
  const int o    = blockIdx.x & 255;
  const float4* src = (const float4*)((widx == 0 ? w0 : (widx == 1 ? w1 : w2)) + (size_t)o * 57600);
  unsigned short* dst = Wp + (size_t)widx * 65 * 65536 + (size_t)o * 256;
  for (int idx4 = threadIdx.x; idx4 < 14400; idx4 += 256){
    float4 val = src[idx4];
    int e = idx4 * 4;
    float vv[4] = {val.x, val.y, val.z, val.w};
#pragma unroll
    for (int j = 0; j < 4; ++j){
      int ee = e + j;
      int i = ee / 225;
      int t = ee - i * 225;
      short c = CMAP.m[t];
      if (c >= 0) sw[c][i] = f2b(vv[j]);
    }
  }
  __syncthreads();
  for (int idx = threadIdx.x; idx < 65 * 128; idx += 256){
    int t = idx >> 7, i2 = idx & 127;
    *(ushort2*)(dst + (size_t)t * 65536 + i2 * 2) = *(const ushort2*)&sw[t][i2 * 2];
  }
}

__global__ void pack_wo_k(const float4* __restrict__ wo, ushort4* __restrict__ WO){
  int i = blockIdx.x * 256 + threadIdx.x;   // 16384 total
  float4 a = wo[i];
  WO[i] = make_ushort4(f2b(a.x), f2b(a.y), f2b(a.z), f2b(a.w));
}

// ---------- input f32 -> bf16 ----------
__global__ void prep_k(const float4* __restrict__ q, const float4* __restrict__ k,
                       const float4* __restrict__ v, ushort4* __restrict__ xq,
                       ushort4* __restrict__ xk, ushort4* __restrict__ xv){
  int i = blockIdx.x * 256 + threadIdx.x;   // 524288 total
  float4 a = q[i]; xq[i] = make_ushort4(f2b(a.x), f2b(a.y), f2b(a.z), f2b(a.w));
  a = k[i];        xk[i] = make_ushort4(f2b(a.x), f2b(a.y), f2b(a.z), f2b(a.w));
  a = v[i];        xv[i] = make_ushort4(f2b(a.x), f2b(a.y), f2b(a.z), f2b(a.w));
}

// ---------- conv as block-gathered GEMM (R6-measured structure, verbatim) ----------
// 768 work items = (64 p, 2 o-half, 6 = branch*2 + batch-half), 256 threads.
// XCD-chunked bijective remap (768%8==0): each XCD owns contiguous
// (o-half,branch,batch-half) groups -> per-XCD L2 working set ~1 W panel.
// Y[b][p][o] = bias[o] + sum_{valid q} sum_i X[b][q][i] * Wp[tap(p,q)][o][i]   (+ReLU)
template<bool RELU>
__global__ __launch_bounds__(256, 3) void conv_mm(
    const unsigned short* __restrict__ X0, const unsigned short* __restrict__ X1,
    const unsigned short* __restrict__ X2,
    const unsigned short* __restrict__ W0, const unsigned short* __restrict__ W1,
    const unsigned short* __restrict__ W2,
    const float* __restrict__ bias0, const float* __restrict__ bias1,
    const float* __restrict__ bias2,
    unsigned short* __restrict__ Yo0, unsigned short* __restrict__ Yo1,
    unsigned short* __restrict__ Yo2)
{
  __shared__ unsigned short lA[2][64 * 64];    // [batch-row 64][i 64] bf16, xor-swizzled
  __shared__ unsigned short lB[2][128 * 64];   // [o-row 128][i 64]
  __shared__ int   qtap[64];
  __shared__ int   nq_sh;

  const int L   = blockIdx.x + 64 * blockIdx.y + 128 * blockIdx.z;
  const int swz = (L & 7) * 96 + (L >> 3);     // XCD-chunked bijective remap
  const int p     = swz & 63;
  const int o0    = ((swz >> 6) & 1) * 128;
  const int zz    = swz >> 7;
  const int br    = zz >> 1;
  const int brow0 = (zz & 1) * 64;
  const unsigned short* X    = br == 0 ? X0 : (br == 1 ? X1 : X2);
  const unsigned short* W    = br == 0 ? W0 : (br == 1 ? W1 : W2);
  const float*          bias = br == 0 ? bias0 : (br == 1 ? bias1 : bias2);
  unsigned short*       Y    = br == 0 ? Yo0 : (br == 1 ? Yo1 : Yo2);

  const int tid = threadIdx.x;
  if (tid == 0){
    int py = p >> 3, px = p & 7, m = 0;
    for (int q = 0; q < 64; ++q){
      int qy = q >> 3, qx = q & 7;
      int t = (7 + qy - py) * 15 + (7 + qx - px);
      short c = CMAP.m[t];
      if (c >= 0) qtap[m++] = (q << 8) | (int)c;
    }
    nq_sh = m;
  }
  __syncthreads();
  const int nq     = nq_sh;
  const int nsteps = nq * 4;

  const int wv_ = tid >> 6, ln = tid & 63;
  const int lr = ln & 15, lk = ln >> 4;
  const int wm = wv_ >> 1, wn = wv_ & 1;
  f32x4 acc[2][4] = {};

  auto stage = [&](int buf, int s){
    int e   = qtap[s >> 2];
    int kkc = (s & 3) * 64;
    int q   = e >> 8, tap = e & 255;
    int r = ln >> 3, c = ln & 7;
#pragma unroll
    for (int r2 = 0; r2 < 2; ++r2){
      int rowb = r2 * 32 + wv_ * 8;
      int row  = rowb + r;
      int csw  = c ^ (row & 7);
      GLDS(X + (size_t)(brow0 + row) * 16384 + q * 256 + kkc + csw * 8, &lA[buf][rowb * 64]);
    }
#pragma unroll
    for (int r2 = 0; r2 < 4; ++r2){
      int rowb = r2 * 32 + wv_ * 8;
      int row  = rowb + r;
      int csw  = c ^ (row & 7);
      GLDS(W + (size_t)tap * 65536 + (size_t)(o0 + row) * 256 + kkc + csw * 8, &lB[buf][rowb * 64]);
    }
  };

  stage(0, 0);
  for (int s = 0; s < nsteps; ++s){
    int buf = s & 1;
    if (s + 1 < nsteps){
      stage(buf ^ 1, s + 1);
      asm volatile("s_waitcnt vmcnt(6)" ::: "memory");
    } else {
      asm volatile("s_waitcnt vmcnt(0)" ::: "memory");
    }
    __builtin_amdgcn_sched_barrier(0);
    __builtin_amdgcn_s_barrier();
#pragma unroll
    for (int ks = 0; ks < 2; ++ks){
      bf16x8 a[2], bb[4];
      int cb = ks * 4 + lk;
#pragma unroll
      for (int mm = 0; mm < 2; ++mm){
        int row = wm * 32 + mm * 16 + lr;
        a[mm] = *(const bf16x8*)&lA[buf][row * 64 + ((cb ^ (row & 7)) << 3)];
      }
#pragma unroll
      for (int nn = 0; nn < 4; ++nn){
        int row = wn * 64 + nn * 16 + lr;
        bb[nn] = *(const bf16x8*)&lB[buf][row * 64 + ((cb ^ (row & 7)) << 3)];
      }
#pragma unroll
      for (int mm = 0; mm < 2; ++mm)
#pragma unroll
        for (int nn = 0; nn < 4; ++nn)
          acc[mm][nn] = __builtin_amdgcn_mfma_f32_16x16x32_bf16(a[mm], bb[nn], acc[mm][nn], 0, 0, 0);
    }
    __builtin_amdgcn_s_barrier();
  }

#pragma unroll
  for (int mm = 0; mm < 2; ++mm)
#pragma unroll
    for (int nn = 0; nn < 4; ++nn)
#pragma unroll
      for (int rr = 0; rr < 4; ++rr){
        int row = wm * 32 + mm * 16 + lk * 4 + rr;   // D: row=(lane>>4)*4+reg
        int col = wn * 64 + nn * 16 + lr;            //    col=lane&15
        int b = brow0 + row, o = o0 + col;
        float val = acc[mm][nn][rr] + bias[o];
        if (RELU) val = fmaxf(val, 0.f);
        Y[(size_t)(b * 64 + p) * 256 + o] = f2b(val);
      }
}

// ---------- attention per (b,h): 64x64 scores, softmax, PV (vectorized) ----------
// Loads as ushort4 -> float4 LDS stores; scores/PV read LDS as float4
// (per-instruction only 4-8 distinct row addresses across the wave ->
// broadcast-friendly); softmax uses ALL 256 threads (4 lanes/row, 16 cols
// each, __shfl_xor(1,2) group reduce).
__global__ __launch_bounds__(256) void attn_k(
    const unsigned short* __restrict__ Yq, const unsigned short* __restrict__ Yk,
    const unsigned short* __restrict__ Yv, unsigned short* __restrict__ CC)
{
  __shared__ float qs[64][36], ksh[64][36], vs[64][36];  // 36: float4-aligned pad
  __shared__ float sc[64][65];
  const int b = blockIdx.x >> 3, h = blockIdx.x & 7;
  const size_t base = (size_t)b * 16384 + h * 32;
  const int tid = threadIdx.x;

  // load: 512 ushort4 per array, 2 iters/thread
  for (int i4 = tid; i4 < 512; i4 += 256){
    int pq = i4 >> 3, c4 = i4 & 7;           // dk = c4*4..c4*4+3
    size_t g = base + (size_t)pq * 256 + c4 * 4;
    ushort4 uq = *(const ushort4*)(Yq + g);
    ushort4 uk = *(const ushort4*)(Yk + g);
    ushort4 uv = *(const ushort4*)(Yv + g);
    *(float4*)&qs[pq][c4 * 4]  = make_float4(b2f(uq.x), b2f(uq.y), b2f(uq.z), b2f(uq.w));
    *(float4*)&ksh[pq][c4 * 4] = make_float4(b2f(uk.x), b2f(uk.y), b2f(uk.z), b2f(uk.w));
    *(float4*)&vs[pq][c4 * 4]  = make_float4(b2f(uv.x), b2f(uv.y), b2f(uv.z), b2f(uv.w));
  }
  __syncthreads();

  const int r  = tid >> 2;      // row 0..63
  const int qd = tid & 3;       // col quarter
  {
    float4 qv[8];
#pragma unroll
    for (int c = 0; c < 8; ++c) qv[c] = *(const float4*)&qs[r][c * 4];
#pragma unroll
    for (int j = 0; j < 16; ++j){
      int pk = qd * 16 + j;
      float a = 0.f;
#pragma unroll
      for (int c = 0; c < 8; ++c){
        float4 kv = *(const float4*)&ksh[pk][c * 4];
        a += qv[c].x * kv.x + qv[c].y * kv.y + qv[c].z * kv.z + qv[c].w * kv.w;
      }
      sc[r][pk] = a * 0.17677669529663687f;  // 1/sqrt(32)
    }
  }
  __syncthreads();

  // softmax: 4 lanes per row, 16 cols each
  {
    float m = -1e30f;
#pragma unroll
    for (int j = 0; j < 16; ++j) m = fmaxf(m, sc[r][qd * 16 + j]);
    m = fmaxf(m, __shfl_xor(m, 1));
    m = fmaxf(m, __shfl_xor(m, 2));
    float e[16], ssum = 0.f;
#pragma unroll
    for (int j = 0; j < 16; ++j){ e[j] = __expf(sc[r][qd * 16 + j] - m); ssum += e[j]; }
    ssum += __shfl_xor(ssum, 1);
    ssum += __shfl_xor(ssum, 2);
    float inv = 1.f / ssum;
#pragma unroll
    for (int j = 0; j < 16; ++j) sc[r][qd * 16 + j] = e[j] * inv;
  }
  __syncthreads();

  // PV: thread owns (pq=r, dk block of 8 = qd*8)
  {
    float o0_[4] = {}, o1_[4] = {};
    const int dk0 = qd * 8;
#pragma unroll
    for (int pk = 0; pk < 64; ++pk){
      float pw = sc[r][pk];
      float4 v0 = *(const float4*)&vs[pk][dk0];
      float4 v1 = *(const float4*)&vs[pk][dk0 + 4];
      o0_[0] += pw * v0.x; o0_[1] += pw * v0.y; o0_[2] += pw * v0.z; o0_[3] += pw * v0.w;
      o1_[0] += pw * v1.x; o1_[1] += pw * v1.y; o1_[2] += pw * v1.z; o1_[3] += pw * v1.w;
    }
    ushort4 u0 = make_ushort4(f2b(o0_[0]), f2b(o0_[1]), f2b(o0_[2]), f2b(o0_[3]));
    ushort4 u1 = make_ushort4(f2b(o1_[0]), f2b(o1_[1]), f2b(o1_[2]), f2b(o1_[3]));
    size_t g = base + (size_t)r * 256 + dk0;
    *(ushort4*)(CC + g)     = u0;
    *(ushort4*)(CC + g + 4) = u1;
  }
}

// ---------- final linear: out[m][o] = sum_c CC[m][c]*wo[o][c] + bo[o] ----------
__global__ __launch_bounds__(256, 3) void fin_mm(
    const unsigned short* __restrict__ A, const unsigned short* __restrict__ Bw,
    const float* __restrict__ bo, float* __restrict__ out)
{
  __shared__ unsigned short lA[2][64 * 64];
  __shared__ unsigned short lB[2][128 * 64];
  const int m0 = blockIdx.x * 64;
  const int o0 = blockIdx.y * 128;
  const int tid = threadIdx.x;
  const int wv_ = tid >> 6, ln = tid & 63;
  const int lr = ln & 15, lk = ln >> 4;
  const int wm = wv_ >> 1, wn = wv_ & 1;
  f32x4 acc[2][4] = {};

  auto stage = [&](int buf, int s){
    int kkc = s * 64;
    int r = ln >> 3, c = ln & 7;
#pragma unroll
    for (int r2 = 0; r2 < 2; ++r2){
      int rowb = r2 * 32 + wv_ * 8;
      int row  = rowb + r;
      int csw  = c ^ (row & 7);
      GLDS(A + (size_t)(m0 + row) * 256 + kkc + csw * 8, &lA[buf][rowb * 64]);
    }
#pragma unroll
    for (int r2 = 0; r2 < 4; ++r2){
      int rowb = r2 * 32 + wv_ * 8;
      int row  = rowb + r;
      int csw  = c ^ (row & 7);
      GLDS(Bw + (size_t)(o0 + row) * 256 + kkc + csw * 8, &lB[buf][rowb * 64]);
    }
  };

  stage(0, 0);
  for (int s = 0; s < 4; ++s){
    int buf = s & 1;
    if (s < 3){
      stage(buf ^ 1, s + 1);
      asm volatile("s_waitcnt vmcnt(6)" ::: "memory");
    } else {
      asm volatile("s_waitcnt vmcnt(0)" ::: "memory");
    }
    __builtin_amdgcn_sched_barrier(0);
    __builtin_amdgcn_s_barrier();
#pragma unroll
    for (int ks = 0; ks < 2; ++ks){
      bf16x8 a[2], bb[4];
      int cb = ks * 4 + lk;
#pragma unroll
      for (int mm = 0; mm < 2; ++mm){
        int row = wm * 32 + mm * 16 + lr;
        a[mm] = *(const bf16x8*)&lA[buf][row * 64 + ((cb ^ (row & 7)) << 3)];
      }
#pragma unroll
      for (int nn = 0; nn < 4; ++nn){
        int row = wn * 64 + nn * 16 + lr;
        bb[nn] = *(const bf16x8*)&lB[buf][row * 64 + ((cb ^ (row & 7)) << 3)];
      }
#pragma unroll
      for (int mm = 0; mm < 2; ++mm)
#pragma unroll
        for (int nn = 0; nn < 4; ++nn)
          acc[mm][nn] = __builtin_amdgcn_mfma_f32_16x16x32_bf16(a[mm], bb[nn], acc[mm][nn], 0, 0, 0);
    }
    __builtin_amdgcn_s_barrier();
  }

#pragma unroll
  for (int mm = 0; mm < 2; ++mm)
#pragma unroll
    for (int nn = 0; nn < 4; ++nn)
#pragma unroll
      for (int rr = 0; rr < 4; ++rr){
        int row = wm * 32 + mm * 16 + lk * 4 + rr;
        int col = wn * 64 + nn * 16 + lr;
        out[(size_t)(m0 + row) * 256 + o0 + col] = acc[mm][nn][rr] + bo[o0 + col];
      }
}

// ---------- launch ----------
extern "C" void kernel_launch(void* const* d_in, const int* in_sizes, int n_in,
                              void* d_out, int out_size, void* d_ws, size_t ws_size,
                              hipStream_t stream){
  const float* q  = (const float*)d_in[0];
  const float* k  = (const float*)d_in[1];
  const float* v  = (const float*)d_in[2];
  const float* wk = (const float*)d_in[3];
  const float* bk = (const float*)d_in[4];
  const float* wq = (const float*)d_in[5];
  const float* bq = (const float*)d_in[6];
  const float* wv = (const float*)d_in[7];
  const float* bv = (const float*)d_in[8];
  const float* wo = (const float*)d_in[9];
  const float* bo = (const float*)d_in[10];
  float* out = (float*)d_out;

  constexpr size_t WPS = 65ull * 65536;   // packed weight elems (ushort)
  constexpr size_t XSZ = 2097152ull;      // [128][64][256] elems

  char* ws = (char*)d_ws;
  size_t off = 0;
  auto alloc = [&](size_t bytes){ void* p = ws + off; off += (bytes + 255) & ~(size_t)255; return p; };
  unsigned short* Wp  = (unsigned short*)alloc(3 * WPS * 2);
  unsigned short* WO  = (unsigned short*)alloc(65536 * 2);
  unsigned short* Xq  = (unsigned short*)alloc(XSZ * 2);
  unsigned short* Xk  = (unsigned short*)alloc(XSZ * 2);
  unsigned short* Xv  = (unsigned short*)alloc(XSZ * 2);
  unsigned short* Y1q = (unsigned short*)alloc(XSZ * 2);
  unsigned short* Y1k = (unsigned short*)alloc(XSZ * 2);
  unsigned short* Y1v = (unsigned short*)alloc(XSZ * 2);
  unsigned short* Y2q = (unsigned short*)alloc(XSZ * 2);
  unsigned short* Y2k = (unsigned short*)alloc(XSZ * 2);
  unsigned short* Y2v = (unsigned short*)alloc(XSZ * 2);
  unsigned short* CC  = (unsigned short*)alloc(XSZ * 2);
  (void)ws_size; (void)in_sizes; (void)n_in; (void)out_size;

  // pack order: widx 0=wq, 1=wk, 2=wv
  pack_w_k<<<dim3(768), 256, 0, stream>>>(wq, wk, wv, Wp);
  pack_wo_k<<<dim3(64), 256, 0, stream>>>((const float4*)wo, (ushort4*)WO);
  prep_k<<<dim3(2048), 256, 0, stream>>>((const float4*)q, (const float4*)k, (const float4*)v,
                                         (ushort4*)Xq, (ushort4*)Xk, (ushort4*)Xv);
  // conv1: q->wq,bq ; k->wk,bk ; v->wv,bv  (+ReLU)
  conv_mm<true><<<dim3(64, 2, 6), 256, 0, stream>>>(
      Xq, Xk, Xv, Wp, Wp + WPS, Wp + 2 * WPS, bq, bk, bv, Y1q, Y1k, Y1v);
  // conv2: q->wk,bk (!) ; k->wk,bk ; v->wv,bv  (no ReLU) — faithful to reference
  conv_mm<false><<<dim3(64, 2, 6), 256, 0, stream>>>(
      Y1q, Y1k, Y1v, Wp + WPS, Wp + WPS, Wp + 2 * WPS, bk, bk, bv, Y2q, Y2k, Y2v);
  attn_k<<<dim3(1024), 256, 0, stream>>>(Y2q, Y2k, Y2v, CC);
  fin_mm<<<dim3(128, 2), 256, 0, stream>>>(CC, WO, bo, out);
}